// Round 3
// baseline (426.370 us; speedup 1.0000x reference)
//
#include <hip/hip_runtime.h>
#include <stdint.h>

typedef unsigned short u16;

#define GAS __attribute__((address_space(1)))
#define LAS __attribute__((address_space(3)))

typedef __bf16 bf16x8 __attribute__((ext_vector_type(8)));
typedef float f32x4 __attribute__((ext_vector_type(4)));

// B=4, T=2048, D_IN=D_OUT=2048. M = 8192, K = 6144, N = 2048.
// ws layout: Z bf16 [8192 x 6144] (96 MB) | Wcat bf16 [2048 x 6144] (24 MB)

__device__ inline u16 f2b(float f) {
    uint32_t x = __float_as_uint(f);
    uint32_t r = (x + 0x7fffu + ((x >> 16) & 1u)) >> 16;
    return (u16)r;
}

__device__ inline float b2f(u16 u) {
    union { uint32_t i; float f; } v;
    v.i = ((uint32_t)u) << 16;
    return v.f;
}

__device__ inline void load8b(float* v, const u16* p) {
    uint4 u = *(const uint4*)p;
    v[0] = b2f((u16)(u.x)); v[1] = b2f((u16)(u.x >> 16));
    v[2] = b2f((u16)(u.y)); v[3] = b2f((u16)(u.y >> 16));
    v[4] = b2f((u16)(u.z)); v[5] = b2f((u16)(u.z >> 16));
    v[6] = b2f((u16)(u.w)); v[7] = b2f((u16)(u.w >> 16));
}

__device__ inline void load8f(float* v, const float* p) {
    float4 a = *(const float4*)p;
    float4 b = *(const float4*)(p + 4);
    v[0] = a.x; v[1] = a.y; v[2] = a.z; v[3] = a.w;
    v[4] = b.x; v[5] = b.y; v[6] = b.z; v[7] = b.w;
}

__device__ inline void store8b(u16* p, const float* v, float scale) {
    uint4 u;
    u.x = (uint32_t)f2b(v[0] * scale) | ((uint32_t)f2b(v[1] * scale) << 16);
    u.y = (uint32_t)f2b(v[2] * scale) | ((uint32_t)f2b(v[3] * scale) << 16);
    u.z = (uint32_t)f2b(v[4] * scale) | ((uint32_t)f2b(v[5] * scale) << 16);
    u.w = (uint32_t)f2b(v[6] * scale) | ((uint32_t)f2b(v[7] * scale) << 16);
    *(uint4*)p = u;
}

__device__ inline float sigmoidf(float v) { return 1.f / (1.f + __expf(-v)); }

__device__ inline float pow64f(float a) {
    float p = a * a;
    p = p * p;
    p = p * p;
    p = p * p;
    p = p * p;
    return p * p;
}

__device__ inline float* carry_ptr(u16* Z, int plane, int b, int c, int d) {
    int f = ((plane * 4 + b) * 32 + c) * 2048 + d;
    int row = f >> 10;
    int off = f & 1023;
    return (float*)(Z + (size_t)row * 6144) + off;
}

// ---------------------------------------------------------------------------
// pack Wp|Wi|Wd (fp32) into Wcat bf16 rows of 6144.
// ---------------------------------------------------------------------------
__global__ __launch_bounds__(256) void pack_w(
    const float* __restrict__ Wp, const float* __restrict__ Wi,
    const float* __restrict__ Wd, u16* __restrict__ Wcat)
{
    int i = (blockIdx.x * 256 + threadIdx.x) * 8;
    int seg = i >> 22;
    int j = i & 4194303;
    const float* src = (seg == 0) ? Wp : (seg == 1) ? Wi : Wd;
    int o = j >> 11;
    int c = j & 2047;
    float v[8];
    load8f(v, src + j);
    store8b(Wcat + (size_t)o * 6144 + seg * 2048 + c, v, 1.0f);
}

// ---------------------------------------------------------------------------
// Scan pass 1: local 64-step scans, zero carry; store end states.
// 2 d-lanes per thread: float2 loads (8 B/lane), float2 carry stores.
// ---------------------------------------------------------------------------
__global__ __launch_bounds__(256) void scan_pass1(
    const float* __restrict__ x, const float* __restrict__ alog,
    const float* __restrict__ blog, u16* __restrict__ Z)
{
    const int d = (blockIdx.x * 256 + threadIdx.x) * 2;
    const int c = blockIdx.y;
    const int b = blockIdx.z;
    const float2 al2 = *(const float2*)(alog + d);
    const float2 bl2 = *(const float2*)(blog + d);
    const float a0 = sigmoidf(al2.x), a1 = sigmoidf(al2.y);
    const float e0 = sigmoidf(bl2.x), e1 = sigmoidf(bl2.y);
    const float oa0 = 1.f - a0, oa1 = 1.f - a1;
    const float oe0 = 1.f - e0, oe1 = 1.f - e1;
    const float* xp = x + ((size_t)b * 2048 + c * 64) * 2048 + d;
    float px0 = 0.f, px1 = 0.f;
    if (c != 0) { float2 t = *(const float2*)(xp - 2048); px0 = t.x; px1 = t.y; }
    float s0 = 0.f, s1 = 0.f, d0 = 0.f, d1 = 0.f;
    #pragma unroll 8
    for (int t = 0; t < 64; ++t) {
        float2 xf = *(const float2*)(xp + (size_t)t * 2048);
        s0 = a0 * s0 + oa0 * xf.x;
        s1 = a1 * s1 + oa1 * xf.y;
        d0 = e0 * d0 + oe0 * (xf.x - px0);
        d1 = e1 * d1 + oe1 * (xf.y - px1);
        px0 = xf.x; px1 = xf.y;
    }
    *(float2*)carry_ptr(Z, 0, b, c, d) = make_float2(s0, s1);
    *(float2*)carry_ptr(Z, 1, b, c, d) = make_float2(d0, d1);
}

// ---------------------------------------------------------------------------
// Scan pass 2: combine 32 chunk carries per (b,d).
// ---------------------------------------------------------------------------
__global__ __launch_bounds__(256) void scan_pass2(
    const float* __restrict__ alog, const float* __restrict__ blog,
    u16* __restrict__ Z)
{
    const int g = blockIdx.x * 256 + threadIdx.x;
    const int b = g >> 11;
    const int d = g & 2047;
    const float aL = pow64f(sigmoidf(alog[d]));
    const float bL = pow64f(sigmoidf(blog[d]));
    float sIn = 0.f, dIn = 0.f;
    for (int c = 0; c < 32; ++c) {
        float* sp = carry_ptr(Z, 0, b, c, d);
        float* dp = carry_ptr(Z, 1, b, c, d);
        float sl = *sp, dl = *dp;
        *sp = sIn; *dp = dIn;
        sIn = sl + aL * sIn;
        dIn = dl + bL * dIn;
    }
}

// ---------------------------------------------------------------------------
// Scan pass 3: exact scan per chunk from carry; write bf16 s,d to Z.
// 2 d-lanes per thread: float2 loads, u32 bf16-pair stores.
// ---------------------------------------------------------------------------
__global__ __launch_bounds__(256) void scan_pass3(
    const float* __restrict__ x, const float* __restrict__ alog,
    const float* __restrict__ blog, u16* __restrict__ Z)
{
    const int d = (blockIdx.x * 256 + threadIdx.x) * 2;
    const int c = blockIdx.y;
    const int b = blockIdx.z;
    const float2 al2 = *(const float2*)(alog + d);
    const float2 bl2 = *(const float2*)(blog + d);
    const float a0 = sigmoidf(al2.x), a1 = sigmoidf(al2.y);
    const float e0 = sigmoidf(bl2.x), e1 = sigmoidf(bl2.y);
    const float oa0 = 1.f - a0, oa1 = 1.f - a1;
    const float oe0 = 1.f - e0, oe1 = 1.f - e1;
    const float* xp = x + ((size_t)b * 2048 + c * 64) * 2048 + d;
    u16* zp = Z + ((size_t)b * 2048 + c * 64) * 6144 + 2048 + d;
    float2 sc = *(const float2*)carry_ptr(Z, 0, b, c, d);
    float2 dc = *(const float2*)carry_ptr(Z, 1, b, c, d);
    float s0 = sc.x, s1 = sc.y, d0 = dc.x, d1 = dc.y;
    float px0 = 0.f, px1 = 0.f;
    if (c != 0) { float2 t = *(const float2*)(xp - 2048); px0 = t.x; px1 = t.y; }
    #pragma unroll 8
    for (int t = 0; t < 64; ++t) {
        float2 xf = *(const float2*)(xp + (size_t)t * 2048);
        s0 = a0 * s0 + oa0 * xf.x;
        s1 = a1 * s1 + oa1 * xf.y;
        d0 = e0 * d0 + oe0 * (xf.x - px0);
        d1 = e1 * d1 + oe1 * (xf.y - px1);
        px0 = xf.x; px1 = xf.y;
        size_t zo = (size_t)t * 6144;
        *(uint32_t*)(zp + zo) = (uint32_t)f2b(s0) | ((uint32_t)f2b(s1) << 16);
        *(uint32_t*)(zp + zo + 2048) = (uint32_t)f2b(d0) | ((uint32_t)f2b(d1) << 16);
    }
}

// ---------------------------------------------------------------------------
// Gates: per-row logits + softmax; write Z row = [g0*x|g1*s|g2*d] bf16.
// ---------------------------------------------------------------------------
__global__ __launch_bounds__(256) void gates_kernel(
    const float* __restrict__ x, const float* __restrict__ Wg,
    const float* __restrict__ Wgb, u16* __restrict__ Z)
{
    const int row = blockIdx.x;
    const int tid = threadIdx.x;
    const int k = tid * 8;
    const float* xr = x + (size_t)row * 2048;
    u16* zr = Z + (size_t)row * 6144;

    float xv[8], sv[8], dv[8];
    load8f(xv, xr + k);
    load8b(sv, zr + 2048 + k);
    load8b(dv, zr + 4096 + k);

    float p[3];
    #pragma unroll
    for (int gg = 0; gg < 3; ++gg) {
        float wx[8], ws[8], wd[8];
        load8f(wx, Wg + gg * 6144 + k);
        load8f(ws, Wg + gg * 6144 + 2048 + k);
        load8f(wd, Wg + gg * 6144 + 4096 + k);
        float acc = 0.f;
        #pragma unroll
        for (int j = 0; j < 8; ++j)
            acc += xv[j] * wx[j] + sv[j] * ws[j] + dv[j] * wd[j];
        p[gg] = acc;
    }

    #pragma unroll
    for (int off = 32; off > 0; off >>= 1) {
        p[0] += __shfl_down(p[0], off);
        p[1] += __shfl_down(p[1], off);
        p[2] += __shfl_down(p[2], off);
    }

    __shared__ float red[4][3];
    __shared__ float gsh[3];
    int wv = tid >> 6, lane = tid & 63;
    if (lane == 0) { red[wv][0] = p[0]; red[wv][1] = p[1]; red[wv][2] = p[2]; }
    __syncthreads();
    if (tid == 0) {
        float l0 = red[0][0] + red[1][0] + red[2][0] + red[3][0] + Wgb[0];
        float l1 = red[0][1] + red[1][1] + red[2][1] + red[3][1] + Wgb[1];
        float l2 = red[0][2] + red[1][2] + red[2][2] + red[3][2] + Wgb[2];
        float m = fmaxf(l0, fmaxf(l1, l2));
        float e0 = __expf(l0 - m), e1 = __expf(l1 - m), e2 = __expf(l2 - m);
        float inv = 1.f / (e0 + e1 + e2);
        gsh[0] = e0 * inv; gsh[1] = e1 * inv; gsh[2] = e2 * inv;
    }
    __syncthreads();
    float g0 = gsh[0], g1 = gsh[1], g2 = gsh[2];
    store8b(zr + k, xv, g0);
    store8b(zr + 2048 + k, sv, g1);
    store8b(zr + 4096 + k, dv, g2);
}

// ---------------------------------------------------------------------------
// GEMM: Y(8192x2048) = Z(8192x6144) @ Wcat^T + bias.  bf16 MFMA.
// 256x256 tile, BK=64, 8 waves (2M x 4N), 512 threads, 128 KiB LDS.
// m201 geometry (round-2, zero-conflict verified): per operand 2 buffers x
// 2 ROW-halves x [128 rows][64 k]u16; LDS chunk c of local row lr holds
// global chunk c^(lr&7); readers ch = (h*4+fq)^(fr&7).
// Round-3 change: ALL 8 gloads for tile t+1 issue in PHASE 0 of tile t
// (ring buf for t+1 is free after tile t-1's final barrier), deadline
// order [B0,B1,B2,B3 | A0,A2 | A1,A3].  Worst-case latency cover rises
// from ~1 phase to 3 phases (~450+ cyc).  Counted waits, never 0:
//   end phase 0: vmcnt(8)  (10 outstanding -> forces A1,A3 of CURRENT
//                           tile, needed by phase 1, issued 4 phases ago)
//   end phase 3: vmcnt(2)  (8 outstanding -> forces the 6 phase-0-needed
//                           loads of tile t+1; leaves its A1,A3 in flight)
// Grid dim3(8,32): blockIdx.x = n-panel -> per-XCD Wcat panel L2 residency.
// ---------------------------------------------------------------------------
__global__ __launch_bounds__(512, 2) void gemm_kernel(
    const u16* __restrict__ Z, const u16* __restrict__ Wcat,
    const float* __restrict__ bias, float* __restrict__ out)
{
    extern __shared__ u16 lds[];
    u16* const lA = lds;           // 4 slots x 8192 u16 (slot = buf*2 + half)
    u16* const lB = lds + 32768;

    const int tid = threadIdx.x;
    const int bn = blockIdx.x * 256;
    const int bm = blockIdx.y * 256;

    // ---- staging invariants ----
    const int sr  = tid >> 3;                      // 0..63
    const int scq = (tid & 7) ^ (sr & 7);
    const u16* aglob = Z    + (size_t)(bm + sr) * 6144 + scq * 8;
    const u16* bglob = Wcat + (size_t)(bn + sr) * 6144 + scq * 8;

    // ---- reader invariants ----
    const int lane = tid & 63;
    const int wv = tid >> 6;
    const int wm = wv & 1;          // A half
    const int wn = wv >> 1;         // B band: half = wn>>1, sub = wn&1
    const int fr = lane & 15;
    const int fq = lane >> 4;
    const int chlo = fq ^ (fr & 7);
    const int aoff = fr * 64 + chlo * 8;                      // u16, K-lo
    const int boff = ((wn & 1) * 64 + fr) * 64 + chlo * 8;
    const int aoffh = aoff ^ 32;                              // K-hi (ch^4)
    const int boffh = boff ^ 32;

    f32x4 acc[8][4] = {};

#define GLOAD(gsrc, ldst)                                                     \
    __builtin_amdgcn_global_load_lds((const GAS uint32_t*)(gsrc),             \
                                     (LAS uint32_t*)(ldst), 16, 0, 0)

    // deadline-ordered 8-load burst for tile jt into buffer bb (0 or 1)
#define STAGE8(jt, bb) do {                                                   \
    const size_t kc_ = (size_t)(jt) * 64;                                     \
    GLOAD(bglob + kc_,                      lB + (bb) * 16384 + tid * 8);     \
    GLOAD(bglob + (size_t) 64 * 6144 + kc_, lB + (bb) * 16384 + 4096 + tid * 8); \
    GLOAD(bglob + (size_t)128 * 6144 + kc_, lB + (bb) * 16384 + 8192 + tid * 8); \
    GLOAD(bglob + (size_t)192 * 6144 + kc_, lB + (bb) * 16384 + 12288 + tid * 8);\
    GLOAD(aglob + kc_,                      lA + (bb) * 16384 + tid * 8);     \
    GLOAD(aglob + (size_t)128 * 6144 + kc_, lA + (bb) * 16384 + 8192 + tid * 8); \
    GLOAD(aglob + (size_t) 64 * 6144 + kc_, lA + (bb) * 16384 + 4096 + tid * 8); \
    GLOAD(aglob + (size_t)192 * 6144 + kc_, lA + (bb) * 16384 + 12288 + tid * 8);\
} while (0)

    // ---- prologue: tile 0 into buf 0; fence the 6 phase-0-needed loads ----
    STAGE8(0, 0);
    asm volatile("s_waitcnt vmcnt(2)" ::: "memory");
    __builtin_amdgcn_s_barrier();

    for (int kt = 0; kt < 96; ++kt) {
        const int pb  = (kt & 1) * 2;
        const int t1  = (kt < 95) ? kt + 1 : 95;   // tail restage (harmless)
        const u16* aS = lA + (pb + wm) * 8192;
        const u16* bS = lB + (pb + (wn >> 1)) * 8192;
        bf16x8 av[4], bv[4];

        // ---- phase 0: K-lo, mf 0-3 ; issue ALL of tile t+1 ----
        #pragma unroll
        for (int i = 0; i < 4; ++i) av[i] = *(const bf16x8*)(aS + aoff + i * 1024);
        #pragma unroll
        for (int j = 0; j < 4; ++j) bv[j] = *(const bf16x8*)(bS + boff + j * 1024);
        STAGE8(t1, (kt & 1) ^ 1);
        __builtin_amdgcn_s_barrier();
        asm volatile("s_waitcnt lgkmcnt(0)" ::: "memory");
        __builtin_amdgcn_s_setprio(1);
        #pragma unroll
        for (int i = 0; i < 4; ++i)
            #pragma unroll
            for (int j = 0; j < 4; ++j)
                acc[i][j] = __builtin_amdgcn_mfma_f32_16x16x32_bf16(
                    av[i], bv[j], acc[i][j], 0, 0, 0);
        __builtin_amdgcn_s_setprio(0);
        asm volatile("s_waitcnt vmcnt(8)" ::: "memory");
        __builtin_amdgcn_s_barrier();

        // ---- phase 1: K-lo, mf 4-7 (reuse bv) ----
        #pragma unroll
        for (int i = 0; i < 4; ++i)
            av[i] = *(const bf16x8*)(aS + aoff + 4096 + i * 1024);
        __builtin_amdgcn_s_barrier();
        asm volatile("s_waitcnt lgkmcnt(0)" ::: "memory");
        __builtin_amdgcn_s_setprio(1);
        #pragma unroll
        for (int i = 0; i < 4; ++i)
            #pragma unroll
            for (int j = 0; j < 4; ++j)
                acc[4 + i][j] = __builtin_amdgcn_mfma_f32_16x16x32_bf16(
                    av[i], bv[j], acc[4 + i][j], 0, 0, 0);
        __builtin_amdgcn_s_setprio(0);
        __builtin_amdgcn_s_barrier();

        // ---- phase 2: K-hi, mf 0-3 ----
        #pragma unroll
        for (int i = 0; i < 4; ++i) av[i] = *(const bf16x8*)(aS + aoffh + i * 1024);
        #pragma unroll
        for (int j = 0; j < 4; ++j) bv[j] = *(const bf16x8*)(bS + boffh + j * 1024);
        __builtin_amdgcn_s_barrier();
        asm volatile("s_waitcnt lgkmcnt(0)" ::: "memory");
        __builtin_amdgcn_s_setprio(1);
        #pragma unroll
        for (int i = 0; i < 4; ++i)
            #pragma unroll
            for (int j = 0; j < 4; ++j)
                acc[i][j] = __builtin_amdgcn_mfma_f32_16x16x32_bf16(
                    av[i], bv[j], acc[i][j], 0, 0, 0);
        __builtin_amdgcn_s_setprio(0);
        __builtin_amdgcn_s_barrier();

        // ---- phase 3: K-hi, mf 4-7 (reuse bv) ----
        #pragma unroll
        for (int i = 0; i < 4; ++i)
            av[i] = *(const bf16x8*)(aS + aoffh + 4096 + i * 1024);
        __builtin_amdgcn_s_barrier();
        asm volatile("s_waitcnt lgkmcnt(0)" ::: "memory");
        __builtin_amdgcn_s_setprio(1);
        #pragma unroll
        for (int i = 0; i < 4; ++i)
            #pragma unroll
            for (int j = 0; j < 4; ++j)
                acc[4 + i][j] = __builtin_amdgcn_mfma_f32_16x16x32_bf16(
                    av[i], bv[j], acc[4 + i][j], 0, 0, 0);
        __builtin_amdgcn_s_setprio(0);
        asm volatile("s_waitcnt vmcnt(2)" ::: "memory");
        __builtin_amdgcn_s_barrier();
    }

    asm volatile("s_waitcnt vmcnt(0)" ::: "memory");

    // epilogue: C layout col = lane&15, row = (lane>>4)*4 + reg.
    #pragma unroll
    for (int j = 0; j < 4; ++j) {
        const int col = bn + wn * 64 + j * 16 + fr;
        const float bb = bias[col];
        #pragma unroll
        for (int mf = 0; mf < 8; ++mf) {
            const int row0 = bm + wm * 128 + mf * 16 + fq * 4;
            #pragma unroll
            for (int r = 0; r < 4; ++r)
                out[(size_t)(row0 + r) * 2048 + col] = acc[mf][j][r] + bb;
        }
    }
#undef STAGE8
#undef GLOAD
}

extern "C" void kernel_launch(void* const* d_in, const int* in_sizes, int n_in,
                              void* d_out, int out_size, void* d_ws, size_t ws_size,
                              hipStream_t stream) {
    const float* x    = (const float*)d_in[0];
    const float* Wp   = (const float*)d_in[1];
    const float* Wi   = (const float*)d_in[2];
    const float* Wd   = (const float*)d_in[3];
    const float* al   = (const float*)d_in[4];
    const float* bl   = (const float*)d_in[5];
    const float* Wg   = (const float*)d_in[6];
    const float* Wgb  = (const float*)d_in[7];
    const float* bias = (const float*)d_in[8];
    float* out = (float*)d_out;

    u16* Z    = (u16*)d_ws;                                    // 96 MB
    u16* Wcat = (u16*)((char*)d_ws + (size_t)8192 * 6144 * 2); // +24 MB

    static bool lds_cfgd = false;
    if (!lds_cfgd) {
        (void)hipFuncSetAttribute((const void*)gemm_kernel,
                                  hipFuncAttributeMaxDynamicSharedMemorySize,
                                  131072);
        lds_cfgd = true;
    }

    pack_w<<<6144, 256, 0, stream>>>(Wp, Wi, Wd, Wcat);
    scan_pass1<<<dim3(4, 32, 4), 256, 0, stream>>>(x, al, bl, Z);
    scan_pass2<<<32, 256, 0, stream>>>(al, bl, Z);
    scan_pass3<<<dim3(4, 32, 4), 256, 0, stream>>>(x, al, bl, Z);
    gates_kernel<<<8192, 256, 0, stream>>>(x, Wg, Wgb, Z);
    gemm_kernel<<<dim3(8, 32), 512, 131072, stream>>>(Z, Wcat, bias, out);
}

// Round 6
// 397.911 us; speedup vs baseline: 1.0715x; 1.0715x over previous
//
#include <hip/hip_runtime.h>
#include <stdint.h>

typedef unsigned short u16;

#define GAS __attribute__((address_space(1)))
#define LAS __attribute__((address_space(3)))

typedef __bf16 bf16x8 __attribute__((ext_vector_type(8)));
typedef float f32x4 __attribute__((ext_vector_type(4)));

// B=4, T=2048, D_IN=D_OUT=2048. M = 8192, K = 6144, N = 2048.
// ws layout: Z bf16 [8192 x 6144] (96 MB) | Wcat bf16 [2048 x 6144] (24 MB)

__device__ inline u16 f2b(float f) {
    uint32_t x = __float_as_uint(f);
    uint32_t r = (x + 0x7fffu + ((x >> 16) & 1u)) >> 16;
    return (u16)r;
}

__device__ inline float b2f(u16 u) {
    union { uint32_t i; float f; } v;
    v.i = ((uint32_t)u) << 16;
    return v.f;
}

__device__ inline void load8b(float* v, const u16* p) {
    uint4 u = *(const uint4*)p;
    v[0] = b2f((u16)(u.x)); v[1] = b2f((u16)(u.x >> 16));
    v[2] = b2f((u16)(u.y)); v[3] = b2f((u16)(u.y >> 16));
    v[4] = b2f((u16)(u.z)); v[5] = b2f((u16)(u.z >> 16));
    v[6] = b2f((u16)(u.w)); v[7] = b2f((u16)(u.w >> 16));
}

__device__ inline void load8f(float* v, const float* p) {
    float4 a = *(const float4*)p;
    float4 b = *(const float4*)(p + 4);
    v[0] = a.x; v[1] = a.y; v[2] = a.z; v[3] = a.w;
    v[4] = b.x; v[5] = b.y; v[6] = b.z; v[7] = b.w;
}

__device__ inline void store8b(u16* p, const float* v, float scale) {
    uint4 u;
    u.x = (uint32_t)f2b(v[0] * scale) | ((uint32_t)f2b(v[1] * scale) << 16);
    u.y = (uint32_t)f2b(v[2] * scale) | ((uint32_t)f2b(v[3] * scale) << 16);
    u.z = (uint32_t)f2b(v[4] * scale) | ((uint32_t)f2b(v[5] * scale) << 16);
    u.w = (uint32_t)f2b(v[6] * scale) | ((uint32_t)f2b(v[7] * scale) << 16);
    *(uint4*)p = u;
}

__device__ inline float sigmoidf(float v) { return 1.f / (1.f + __expf(-v)); }

__device__ inline float pow64f(float a) {
    float p = a * a;
    p = p * p;
    p = p * p;
    p = p * p;
    p = p * p;
    return p * p;
}

__device__ inline float* carry_ptr(u16* Z, int plane, int b, int c, int d) {
    int f = ((plane * 4 + b) * 32 + c) * 2048 + d;
    int row = f >> 10;
    int off = f & 1023;
    return (float*)(Z + (size_t)row * 6144) + off;
}

// ---------------------------------------------------------------------------
// pack Wp|Wi|Wd (fp32) into Wcat bf16 rows of 6144.
// ---------------------------------------------------------------------------
__global__ __launch_bounds__(256) void pack_w(
    const float* __restrict__ Wp, const float* __restrict__ Wi,
    const float* __restrict__ Wd, u16* __restrict__ Wcat)
{
    int i = (blockIdx.x * 256 + threadIdx.x) * 8;
    int seg = i >> 22;
    int j = i & 4194303;
    const float* src = (seg == 0) ? Wp : (seg == 1) ? Wi : Wd;
    int o = j >> 11;
    int c = j & 2047;
    float v[8];
    load8f(v, src + j);
    store8b(Wcat + (size_t)o * 6144 + seg * 2048 + c, v, 1.0f);
}

// ---------------------------------------------------------------------------
// Scan pass 1: local 64-step scans, zero carry; store end states.
// 2 d-lanes per thread: float2 loads (8 B/lane), float2 carry stores.
// (verbatim round-3: ran+passed)
// ---------------------------------------------------------------------------
__global__ __launch_bounds__(256) void scan_pass1(
    const float* __restrict__ x, const float* __restrict__ alog,
    const float* __restrict__ blog, u16* __restrict__ Z)
{
    const int d = (blockIdx.x * 256 + threadIdx.x) * 2;
    const int c = blockIdx.y;
    const int b = blockIdx.z;
    const float2 al2 = *(const float2*)(alog + d);
    const float2 bl2 = *(const float2*)(blog + d);
    const float a0 = sigmoidf(al2.x), a1 = sigmoidf(al2.y);
    const float e0 = sigmoidf(bl2.x), e1 = sigmoidf(bl2.y);
    const float oa0 = 1.f - a0, oa1 = 1.f - a1;
    const float oe0 = 1.f - e0, oe1 = 1.f - e1;
    const float* xp = x + ((size_t)b * 2048 + c * 64) * 2048 + d;
    float px0 = 0.f, px1 = 0.f;
    if (c != 0) { float2 t = *(const float2*)(xp - 2048); px0 = t.x; px1 = t.y; }
    float s0 = 0.f, s1 = 0.f, d0 = 0.f, d1 = 0.f;
    #pragma unroll 8
    for (int t = 0; t < 64; ++t) {
        float2 xf = *(const float2*)(xp + (size_t)t * 2048);
        s0 = a0 * s0 + oa0 * xf.x;
        s1 = a1 * s1 + oa1 * xf.y;
        d0 = e0 * d0 + oe0 * (xf.x - px0);
        d1 = e1 * d1 + oe1 * (xf.y - px1);
        px0 = xf.x; px1 = xf.y;
    }
    *(float2*)carry_ptr(Z, 0, b, c, d) = make_float2(s0, s1);
    *(float2*)carry_ptr(Z, 1, b, c, d) = make_float2(d0, d1);
}

// ---------------------------------------------------------------------------
// Scan pass 2: combine 32 chunk carries per (b,d).
// ---------------------------------------------------------------------------
__global__ __launch_bounds__(256) void scan_pass2(
    const float* __restrict__ alog, const float* __restrict__ blog,
    u16* __restrict__ Z)
{
    const int g = blockIdx.x * 256 + threadIdx.x;
    const int b = g >> 11;
    const int d = g & 2047;
    const float aL = pow64f(sigmoidf(alog[d]));
    const float bL = pow64f(sigmoidf(blog[d]));
    float sIn = 0.f, dIn = 0.f;
    for (int c = 0; c < 32; ++c) {
        float* sp = carry_ptr(Z, 0, b, c, d);
        float* dp = carry_ptr(Z, 1, b, c, d);
        float sl = *sp, dl = *dp;
        *sp = sIn; *dp = dIn;
        sIn = sl + aL * sIn;
        dIn = dl + bL * dIn;
    }
}

// ---------------------------------------------------------------------------
// Scan pass 3: exact scan per chunk from carry; write bf16 s,d to Z.
// 2 d-lanes per thread: float2 loads, u32 bf16-pair stores.
// (verbatim round-3: ran+passed)
// ---------------------------------------------------------------------------
__global__ __launch_bounds__(256) void scan_pass3(
    const float* __restrict__ x, const float* __restrict__ alog,
    const float* __restrict__ blog, u16* __restrict__ Z)
{
    const int d = (blockIdx.x * 256 + threadIdx.x) * 2;
    const int c = blockIdx.y;
    const int b = blockIdx.z;
    const float2 al2 = *(const float2*)(alog + d);
    const float2 bl2 = *(const float2*)(blog + d);
    const float a0 = sigmoidf(al2.x), a1 = sigmoidf(al2.y);
    const float e0 = sigmoidf(bl2.x), e1 = sigmoidf(bl2.y);
    const float oa0 = 1.f - a0, oa1 = 1.f - a1;
    const float oe0 = 1.f - e0, oe1 = 1.f - e1;
    const float* xp = x + ((size_t)b * 2048 + c * 64) * 2048 + d;
    u16* zp = Z + ((size_t)b * 2048 + c * 64) * 6144 + 2048 + d;
    float2 sc = *(const float2*)carry_ptr(Z, 0, b, c, d);
    float2 dc = *(const float2*)carry_ptr(Z, 1, b, c, d);
    float s0 = sc.x, s1 = sc.y, d0 = dc.x, d1 = dc.y;
    float px0 = 0.f, px1 = 0.f;
    if (c != 0) { float2 t = *(const float2*)(xp - 2048); px0 = t.x; px1 = t.y; }
    #pragma unroll 8
    for (int t = 0; t < 64; ++t) {
        float2 xf = *(const float2*)(xp + (size_t)t * 2048);
        s0 = a0 * s0 + oa0 * xf.x;
        s1 = a1 * s1 + oa1 * xf.y;
        d0 = e0 * d0 + oe0 * (xf.x - px0);
        d1 = e1 * d1 + oe1 * (xf.y - px1);
        px0 = xf.x; px1 = xf.y;
        size_t zo = (size_t)t * 6144;
        *(uint32_t*)(zp + zo) = (uint32_t)f2b(s0) | ((uint32_t)f2b(s1) << 16);
        *(uint32_t*)(zp + zo + 2048) = (uint32_t)f2b(d0) | ((uint32_t)f2b(d1) << 16);
    }
}

// ---------------------------------------------------------------------------
// Gates: per-row logits + softmax; write Z row = [g0*x|g1*s|g2*d] bf16.
// ---------------------------------------------------------------------------
__global__ __launch_bounds__(256) void gates_kernel(
    const float* __restrict__ x, const float* __restrict__ Wg,
    const float* __restrict__ Wgb, u16* __restrict__ Z)
{
    const int row = blockIdx.x;
    const int tid = threadIdx.x;
    const int k = tid * 8;
    const float* xr = x + (size_t)row * 2048;
    u16* zr = Z + (size_t)row * 6144;

    float xv[8], sv[8], dv[8];
    load8f(xv, xr + k);
    load8b(sv, zr + 2048 + k);
    load8b(dv, zr + 4096 + k);

    float p[3];
    #pragma unroll
    for (int gg = 0; gg < 3; ++gg) {
        float wx[8], ws[8], wd[8];
        load8f(wx, Wg + gg * 6144 + k);
        load8f(ws, Wg + gg * 6144 + 2048 + k);
        load8f(wd, Wg + gg * 6144 + 4096 + k);
        float acc = 0.f;
        #pragma unroll
        for (int j = 0; j < 8; ++j)
            acc += xv[j] * wx[j] + sv[j] * ws[j] + dv[j] * wd[j];
        p[gg] = acc;
    }

    #pragma unroll
    for (int off = 32; off > 0; off >>= 1) {
        p[0] += __shfl_down(p[0], off);
        p[1] += __shfl_down(p[1], off);
        p[2] += __shfl_down(p[2], off);
    }

    __shared__ float red[4][3];
    __shared__ float gsh[3];
    int wv = tid >> 6, lane = tid & 63;
    if (lane == 0) { red[wv][0] = p[0]; red[wv][1] = p[1]; red[wv][2] = p[2]; }
    __syncthreads();
    if (tid == 0) {
        float l0 = red[0][0] + red[1][0] + red[2][0] + red[3][0] + Wgb[0];
        float l1 = red[0][1] + red[1][1] + red[2][1] + red[3][1] + Wgb[1];
        float l2 = red[0][2] + red[1][2] + red[2][2] + red[3][2] + Wgb[2];
        float m = fmaxf(l0, fmaxf(l1, l2));
        float e0 = __expf(l0 - m), e1 = __expf(l1 - m), e2 = __expf(l2 - m);
        float inv = 1.f / (e0 + e1 + e2);
        gsh[0] = e0 * inv; gsh[1] = e1 * inv; gsh[2] = e2 * inv;
    }
    __syncthreads();
    float g0 = gsh[0], g1 = gsh[1], g2 = gsh[2];
    store8b(zr + k, xv, g0);
    store8b(zr + 2048 + k, sv, g1);
    store8b(zr + 4096 + k, dv, g2);
}

// ---------------------------------------------------------------------------
// GEMM: Y(8192x2048) = Z(8192x6144) @ Wcat^T + bias.  bf16 MFMA.
// VERBATIM round-2 kernel (harness-verified: 182 us, MfmaUtil 51%,
// SQ_LDS_BANK_CONFLICT = 0, passed).
// 256x256 tile, BK=64, 8 waves (2M x 4N), 512 threads, 128 KiB LDS.
// m201 geometry: per operand 2 buffers x 2 ROW-halves x [128 rows][64 k]u16
// (16 KB slots, 128 B row stride, zero-conflict swizzle: LDS chunk c of
// local row lr holds global chunk c^(lr&7); readers ch = (h*4+fq)^(fr&7)).
// Staging: 8 x global_load_lds (16B, 64 rows each) per tile, pre-swizzled
// global source, issued 2/phase one tile ahead in deadline order
// [B0 | B1 | A-g0s | A-g1s].  Counted waits, never 0:
//   end of phase 0: vmcnt(2)  (fences CURRENT tile's A rows 64-127)
//   end of phase 3: vmcnt(2)  (fences next tile's B + A rows 0-63)
// Grid dim3(8,32): blockIdx.x = n-panel -> per-XCD Wcat panel L2 residency.
// ---------------------------------------------------------------------------
__global__ __launch_bounds__(512, 2) void gemm_kernel(
    const u16* __restrict__ Z, const u16* __restrict__ Wcat,
    const float* __restrict__ bias, float* __restrict__ out)
{
    extern __shared__ u16 lds[];
    u16* const lA = lds;           // 4 slots x 8192 u16 (slot = buf*2 + half)
    u16* const lB = lds + 32768;

    const int tid = threadIdx.x;
    const int bn = blockIdx.x * 256;
    const int bm = blockIdx.y * 256;

    // ---- staging invariants ----
    const int sr  = tid >> 3;                      // 0..63
    const int scq = (tid & 7) ^ (sr & 7);
    const u16* aglob = Z    + (size_t)(bm + sr) * 6144 + scq * 8;
    const u16* bglob = Wcat + (size_t)(bn + sr) * 6144 + scq * 8;

    // ---- reader invariants ----
    const int lane = tid & 63;
    const int wv = tid >> 6;
    const int wm = wv & 1;          // A half
    const int wn = wv >> 1;         // B band: half = wn>>1, sub = wn&1
    const int fr = lane & 15;
    const int fq = lane >> 4;
    const int chlo = fq ^ (fr & 7);
    const int aoff = fr * 64 + chlo * 8;                      // u16, K-lo
    const int boff = ((wn & 1) * 64 + fr) * 64 + chlo * 8;
    const int aoffh = aoff ^ 32;                              // K-hi (ch^4)
    const int boffh = boff ^ 32;

    f32x4 acc[8][4] = {};

#define GLOAD(gsrc, ldst)                                                     \
    __builtin_amdgcn_global_load_lds((const GAS uint32_t*)(gsrc),             \
                                     (LAS uint32_t*)(ldst), 16, 0, 0)

    // ---- prologue: tile 0 into buf 0, deadline order, then vmcnt(2) ----
    GLOAD(bglob,                        lB + tid * 8);
    GLOAD(bglob + (size_t) 64 * 6144,   lB + 4096 + tid * 8);
    GLOAD(bglob + (size_t)128 * 6144,   lB + 8192 + tid * 8);
    GLOAD(bglob + (size_t)192 * 6144,   lB + 8192 + 4096 + tid * 8);
    GLOAD(aglob,                        lA + tid * 8);
    GLOAD(aglob + (size_t)128 * 6144,   lA + 8192 + tid * 8);
    GLOAD(aglob + (size_t) 64 * 6144,   lA + 4096 + tid * 8);
    GLOAD(aglob + (size_t)192 * 6144,   lA + 8192 + 4096 + tid * 8);
    asm volatile("s_waitcnt vmcnt(2)" ::: "memory");
    __builtin_amdgcn_s_barrier();

    for (int kt = 0; kt < 96; ++kt) {
        const int pb  = (kt & 1) * 2;
        const int nbb = pb ^ 2;
        const int t1  = (kt < 95) ? kt + 1 : 95;   // tail restage (harmless)
        const size_t kc = (size_t)t1 * 64;
        const u16* aS = lA + (pb + wm) * 8192;
        const u16* bS = lB + (pb + (wn >> 1)) * 8192;
        bf16x8 av[4], bv[4];

        // ---- phase 0: K-lo, mf 0-3 ----
        #pragma unroll
        for (int i = 0; i < 4; ++i) av[i] = *(const bf16x8*)(aS + aoff + i * 1024);
        #pragma unroll
        for (int j = 0; j < 4; ++j) bv[j] = *(const bf16x8*)(bS + boff + j * 1024);
        GLOAD(bglob + kc,                      lB + nbb * 8192 + tid * 8);
        GLOAD(bglob + (size_t)64 * 6144 + kc,  lB + nbb * 8192 + 4096 + tid * 8);
        __builtin_amdgcn_s_barrier();
        asm volatile("s_waitcnt lgkmcnt(0)" ::: "memory");
        __builtin_amdgcn_s_setprio(1);
        #pragma unroll
        for (int i = 0; i < 4; ++i)
            #pragma unroll
            for (int j = 0; j < 4; ++j)
                acc[i][j] = __builtin_amdgcn_mfma_f32_16x16x32_bf16(
                    av[i], bv[j], acc[i][j], 0, 0, 0);
        __builtin_amdgcn_s_setprio(0);
        asm volatile("s_waitcnt vmcnt(2)" ::: "memory");
        __builtin_amdgcn_s_barrier();

        // ---- phase 1: K-lo, mf 4-7 (reuse bv) ----
        #pragma unroll
        for (int i = 0; i < 4; ++i)
            av[i] = *(const bf16x8*)(aS + aoff + 4096 + i * 1024);
        GLOAD(bglob + (size_t)128 * 6144 + kc, lB + (nbb + 1) * 8192 + tid * 8);
        GLOAD(bglob + (size_t)192 * 6144 + kc, lB + (nbb + 1) * 8192 + 4096 + tid * 8);
        __builtin_amdgcn_s_barrier();
        asm volatile("s_waitcnt lgkmcnt(0)" ::: "memory");
        __builtin_amdgcn_s_setprio(1);
        #pragma unroll
        for (int i = 0; i < 4; ++i)
            #pragma unroll
            for (int j = 0; j < 4; ++j)
                acc[4 + i][j] = __builtin_amdgcn_mfma_f32_16x16x32_bf16(
                    av[i], bv[j], acc[4 + i][j], 0, 0, 0);
        __builtin_amdgcn_s_setprio(0);
        __builtin_amdgcn_s_barrier();

        // ---- phase 2: K-hi, mf 0-3 ----
        #pragma unroll
        for (int i = 0; i < 4; ++i) av[i] = *(const bf16x8*)(aS + aoffh + i * 1024);
        #pragma unroll
        for (int j = 0; j < 4; ++j) bv[j] = *(const bf16x8*)(bS + boffh + j * 1024);
        GLOAD(aglob + kc,                      lA + nbb * 8192 + tid * 8);
        GLOAD(aglob + (size_t)128 * 6144 + kc, lA + (nbb + 1) * 8192 + tid * 8);
        __builtin_amdgcn_s_barrier();
        asm volatile("s_waitcnt lgkmcnt(0)" ::: "memory");
        __builtin_amdgcn_s_setprio(1);
        #pragma unroll
        for (int i = 0; i < 4; ++i)
            #pragma unroll
            for (int j = 0; j < 4; ++j)
                acc[i][j] = __builtin_amdgcn_mfma_f32_16x16x32_bf16(
                    av[i], bv[j], acc[i][j], 0, 0, 0);
        __builtin_amdgcn_s_setprio(0);
        __builtin_amdgcn_s_barrier();

        // ---- phase 3: K-hi, mf 4-7 (reuse bv) ----
        #pragma unroll
        for (int i = 0; i < 4; ++i)
            av[i] = *(const bf16x8*)(aS + aoffh + 4096 + i * 1024);
        GLOAD(aglob + (size_t) 64 * 6144 + kc, lA + nbb * 8192 + 4096 + tid * 8);
        GLOAD(aglob + (size_t)192 * 6144 + kc, lA + (nbb + 1) * 8192 + 4096 + tid * 8);
        __builtin_amdgcn_s_barrier();
        asm volatile("s_waitcnt lgkmcnt(0)" ::: "memory");
        __builtin_amdgcn_s_setprio(1);
        #pragma unroll
        for (int i = 0; i < 4; ++i)
            #pragma unroll
            for (int j = 0; j < 4; ++j)
                acc[4 + i][j] = __builtin_amdgcn_mfma_f32_16x16x32_bf16(
                    av[i], bv[j], acc[4 + i][j], 0, 0, 0);
        __builtin_amdgcn_s_setprio(0);
        asm volatile("s_waitcnt vmcnt(2)" ::: "memory");
        __builtin_amdgcn_s_barrier();
    }

    asm volatile("s_waitcnt vmcnt(0)" ::: "memory");

    // epilogue: C layout col = lane&15, row = (lane>>4)*4 + reg.
    #pragma unroll
    for (int j = 0; j < 4; ++j) {
        const int col = bn + wn * 64 + j * 16 + fr;
        const float bb = bias[col];
        #pragma unroll
        for (int mf = 0; mf < 8; ++mf) {
            const int row0 = bm + wm * 128 + mf * 16 + fq * 4;
            #pragma unroll
            for (int r = 0; r < 4; ++r)
                out[(size_t)(row0 + r) * 2048 + col] = acc[mf][j][r] + bb;
        }
    }
#undef GLOAD
}

extern "C" void kernel_launch(void* const* d_in, const int* in_sizes, int n_in,
                              void* d_out, int out_size, void* d_ws, size_t ws_size,
                              hipStream_t stream) {
    const float* x    = (const float*)d_in[0];
    const float* Wp   = (const float*)d_in[1];
    const float* Wi   = (const float*)d_in[2];
    const float* Wd   = (const float*)d_in[3];
    const float* al   = (const float*)d_in[4];
    const float* bl   = (const float*)d_in[5];
    const float* Wg   = (const float*)d_in[6];
    const float* Wgb  = (const float*)d_in[7];
    const float* bias = (const float*)d_in[8];
    float* out = (float*)d_out;

    u16* Z    = (u16*)d_ws;                                    // 96 MB
    u16* Wcat = (u16*)((char*)d_ws + (size_t)8192 * 6144 * 2); // +24 MB

    static bool lds_cfgd = false;
    if (!lds_cfgd) {
        (void)hipFuncSetAttribute((const void*)gemm_kernel,
                                  hipFuncAttributeMaxDynamicSharedMemorySize,
                                  131072);
        lds_cfgd = true;
    }

    pack_w<<<6144, 256, 0, stream>>>(Wp, Wi, Wd, Wcat);
    scan_pass1<<<dim3(4, 32, 4), 256, 0, stream>>>(x, al, bl, Z);
    scan_pass2<<<32, 256, 0, stream>>>(al, bl, Z);
    scan_pass3<<<dim3(4, 32, 4), 256, 0, stream>>>(x, al, bl, Z);
    gates_kernel<<<8192, 256, 0, stream>>>(x, Wg, Wgb, Z);
    gemm_kernel<<<dim3(8, 32), 512, 131072, stream>>>(Z, Wcat, bias, out);
}